// Round 1
// baseline (467.639 us; speedup 1.0000x reference)
//
#include <hip/hip_runtime.h>

#define B 16
#define S 2048
#define D 256

// Kernel 1: per-row projections. One 64-lane wave per (b,s) row.
// lane l handles d = 4l..4l+3 (64*4 = 256 = D exactly).
__global__ __launch_bounds__(256) void rowdot_kernel(
    const float* __restrict__ x,     // [B*S, D]
    const float* __restrict__ W,     // [2*D]
    const float* __restrict__ bptr,  // [1]
    float* __restrict__ si,          // [B*S]  (stores si + b)
    float* __restrict__ sj)          // [B*S]
{
    const int wave = (blockIdx.x * blockDim.x + threadIdx.x) >> 6;
    const int lane = threadIdx.x & 63;
    if (wave >= B * S) return;

    const float4 xv = *reinterpret_cast<const float4*>(x + (size_t)wave * D + lane * 4);
    const float4 wi = *reinterpret_cast<const float4*>(W + lane * 4);
    const float4 wj = *reinterpret_cast<const float4*>(W + D + lane * 4);

    float a = xv.x * wi.x + xv.y * wi.y + xv.z * wi.z + xv.w * wi.w;
    float c = xv.x * wj.x + xv.y * wj.y + xv.z * wj.z + xv.w * wj.w;

    #pragma unroll
    for (int m = 32; m >= 1; m >>= 1) {
        a += __shfl_xor(a, m, 64);
        c += __shfl_xor(c, m, 64);
    }
    if (lane == 0) {
        si[wave] = a + bptr[0];   // fold bias into si once
        sj[wave] = c;
    }
}

__device__ __forceinline__ float blend_one(float arg, float adjv, int m) {
    // sigmoid(arg) = 1 / (1 + 2^(-arg*log2(e))) via HW v_exp_f32 / v_rcp_f32
    const float e   = __builtin_amdgcn_exp2f(-1.44269504088896f * arg);
    const float sig = __builtin_amdgcn_rcpf(1.0f + e);
    const float v   = 0.6f * sig + 0.4f * adjv;
    return m ? v : 1e-9f;
}

// Kernel 2: elementwise over B*S*S, float4 per thread-iteration.
__global__ __launch_bounds__(256) void fuse_kernel(
    const float* __restrict__ adj,   // [B, S, S]
    const int*   __restrict__ mask,  // [B, S]
    const float* __restrict__ si,    // [B*S] (si + b)
    const float* __restrict__ sj,    // [B*S]
    float* __restrict__ out)         // [B, S, S]
{
    const long long total4 = (long long)B * S * S / 4;
    const long long stride = (long long)gridDim.x * blockDim.x;
    for (long long idx = (long long)blockIdx.x * blockDim.x + threadIdx.x;
         idx < total4; idx += stride) {
        const long long e = idx << 2;              // flat element index
        const int j0 = (int)(e & (S - 1));         // e % 2048
        const int i  = (int)((e >> 11) & (S - 1)); // (e / 2048) % 2048
        const int bb = (int)(e >> 22);             // e / (2048*2048)

        const float4 a4  = *reinterpret_cast<const float4*>(adj + e);
        const float  s_i = si[bb * S + i];
        const float4 sj4 = *reinterpret_cast<const float4*>(sj + bb * S + j0);
        const int    mi  = mask[bb * S + i];
        const int4   mj4 = *reinterpret_cast<const int4*>(mask + bb * S + j0);

        float4 o;
        o.x = blend_one(s_i + sj4.x, a4.x, mi * mj4.x);
        o.y = blend_one(s_i + sj4.y, a4.y, mi * mj4.y);
        o.z = blend_one(s_i + sj4.z, a4.z, mi * mj4.z);
        o.w = blend_one(s_i + sj4.w, a4.w, mi * mj4.w);

        *reinterpret_cast<float4*>(out + e) = o;
    }
}

extern "C" void kernel_launch(void* const* d_in, const int* in_sizes, int n_in,
                              void* d_out, int out_size, void* d_ws, size_t ws_size,
                              hipStream_t stream) {
    const float* x    = (const float*)d_in[0];
    const float* adj  = (const float*)d_in[1];
    const int*   mask = (const int*)d_in[2];
    const float* W    = (const float*)d_in[3];
    const float* bptr = (const float*)d_in[4];
    float* out = (float*)d_out;

    float* si = (float*)d_ws;           // B*S floats
    float* sj = si + (size_t)B * S;     // B*S floats  (512 KB total << ws)

    // Kernel 1: one wave per row, 4 waves per block -> B*S/4 blocks.
    rowdot_kernel<<<(B * S) / 4, 256, 0, stream>>>(x, W, bptr, si, sj);

    // Kernel 2: memory-bound grid-stride; 2048 blocks saturates 256 CUs.
    fuse_kernel<<<2048, 256, 0, stream>>>(adj, mask, si, sj, out);
}

// Round 3
// 426.764 us; speedup vs baseline: 1.0958x; 1.0958x over previous
//
#include <hip/hip_runtime.h>

#define B 16
#define S 2048
#define D 256

typedef float fx4 __attribute__((ext_vector_type(4)));
typedef int   ix4 __attribute__((ext_vector_type(4)));

// Kernel 1: per-row projections. One 64-lane wave per (b,s) row.
// lane l handles d = 4l..4l+3 (64*4 = 256 = D exactly).
__global__ __launch_bounds__(256) void rowdot_kernel(
    const float* __restrict__ x,     // [B*S, D]
    const float* __restrict__ W,     // [2*D]
    const float* __restrict__ bptr,  // [1]
    float* __restrict__ si,          // [B*S]  (stores si + b)
    float* __restrict__ sj)          // [B*S]
{
    const int wave = (blockIdx.x * blockDim.x + threadIdx.x) >> 6;
    const int lane = threadIdx.x & 63;
    if (wave >= B * S) return;

    const fx4 xv = *reinterpret_cast<const fx4*>(x + (size_t)wave * D + lane * 4);
    const fx4 wi = *reinterpret_cast<const fx4*>(W + lane * 4);
    const fx4 wj = *reinterpret_cast<const fx4*>(W + D + lane * 4);

    float a = xv.x * wi.x + xv.y * wi.y + xv.z * wi.z + xv.w * wi.w;
    float c = xv.x * wj.x + xv.y * wj.y + xv.z * wj.z + xv.w * wj.w;

    #pragma unroll
    for (int m = 32; m >= 1; m >>= 1) {
        a += __shfl_xor(a, m, 64);
        c += __shfl_xor(c, m, 64);
    }
    if (lane == 0) {
        si[wave] = a + bptr[0];   // fold bias into si once
        sj[wave] = c;
    }
}

__device__ __forceinline__ float blend_one(float arg, float adjv, int m) {
    // sigmoid(arg) = 1 / (1 + 2^(-arg*log2(e))) via HW v_exp_f32 / v_rcp_f32
    const float e   = __builtin_amdgcn_exp2f(-1.44269504088896f * arg);
    const float sig = __builtin_amdgcn_rcpf(1.0f + e);
    const float v   = 0.6f * sig + 0.4f * adjv;
    return m ? v : 1e-9f;
}

// Kernel 2: one block per (b,i) output row of 2048 elements.
// mask_i == 0  -> entire row is 1e-9: write-only, no adj/sj reads.
// mask_i == 1  -> streaming blend; nontemporal adj load + out store.
__global__ __launch_bounds__(256) void fuse_kernel(
    const float* __restrict__ adj,   // [B, S, S]
    const int*   __restrict__ mask,  // [B, S]
    const float* __restrict__ si,    // [B*S] (si + b)
    const float* __restrict__ sj,    // [B*S]
    float* __restrict__ out)         // [B, S, S]
{
    const int row  = blockIdx.x;          // 0 .. B*S-1
    const int bb   = row >> 11;           // row / S
    const long long base = (long long)row << 11;  // row * S
    const int t = threadIdx.x;

    const int mi = mask[row];             // block-uniform
    if (mi == 0) {
        const fx4 fill = {1e-9f, 1e-9f, 1e-9f, 1e-9f};
        #pragma unroll
        for (int k = 0; k < 2; ++k) {
            const int j = (t + (k << 8)) << 2;    // 0..2044 step 4
            __builtin_nontemporal_store(fill,
                reinterpret_cast<fx4*>(out + base + j));
        }
        return;
    }

    const float s_i = si[row];            // block-uniform scalar
    const int jbase = bb << 11;           // bb * S
    #pragma unroll
    for (int k = 0; k < 2; ++k) {
        const int j = (t + (k << 8)) << 2;
        const fx4 a4  = __builtin_nontemporal_load(
            reinterpret_cast<const fx4*>(adj + base + j));
        const fx4 sj4 = *reinterpret_cast<const fx4*>(sj + jbase + j);
        const ix4 mj4 = *reinterpret_cast<const ix4*>(mask + jbase + j);

        fx4 o;
        o.x = blend_one(s_i + sj4.x, a4.x, mj4.x);
        o.y = blend_one(s_i + sj4.y, a4.y, mj4.y);
        o.z = blend_one(s_i + sj4.z, a4.z, mj4.z);
        o.w = blend_one(s_i + sj4.w, a4.w, mj4.w);

        __builtin_nontemporal_store(o, reinterpret_cast<fx4*>(out + base + j));
    }
}

extern "C" void kernel_launch(void* const* d_in, const int* in_sizes, int n_in,
                              void* d_out, int out_size, void* d_ws, size_t ws_size,
                              hipStream_t stream) {
    const float* x    = (const float*)d_in[0];
    const float* adj  = (const float*)d_in[1];
    const int*   mask = (const int*)d_in[2];
    const float* W    = (const float*)d_in[3];
    const float* bptr = (const float*)d_in[4];
    float* out = (float*)d_out;

    float* si = (float*)d_ws;           // B*S floats
    float* sj = si + (size_t)B * S;     // B*S floats  (256 KB total << ws)

    // Kernel 1: one wave per row, 4 waves per block -> B*S/4 blocks.
    rowdot_kernel<<<(B * S) / 4, 256, 0, stream>>>(x, W, bptr, si, sj);

    // Kernel 2: one block per output row.
    fuse_kernel<<<B * S, 256, 0, stream>>>(adj, mask, si, sj, out);
}